// Round 12
// baseline (23533.720 us; speedup 1.0000x reference)
//
#include <hip/hip_runtime.h>

// Problem constants
constexpr int kB     = 32;
constexpr int kLAT   = 512;
constexpr int kCH    = 1024;
constexpr int kCO    = 512;
constexpr int kINP   = 389;
constexpr int kH     = 1024;
constexpr int kSEQ   = 128;
constexpr int kNSUB  = 8;
constexpr int kSTEPS = 16;

#define NBLK 512
#define NTHR 256

// ---------------------------------------------------------------------------
// R12 = MEASUREMENT ROUND. Byte-identical to R11 (16.12ms PASS) except every
// gridbar is executed TWICE. The second barrier has no work between -> its
// marginal cost = pure (barrier mechanics + fences), excluding skew and
// in-phase load latency. B = (dur - 16.12ms)/416 discriminates:
//   H1 barrier-dominated (B~30us -> dur ~29ms): attack barrier next.
//   H2 in-phase-latency-dominated (B~3-12us -> dur ~17.5-21ms): attack MLP.
// ---------------------------------------------------------------------------

__device__ uint g_cWhh0f[4096 * 512];
__device__ uint g_cWih1f[4096 * 512];
__device__ uint g_cWhh1f[4096 * 512];
__device__ uint g_dWih0f[4096 * 456];
__device__ uint g_dWhh0f[4096 * 512];
__device__ uint g_dWih1f[4096 * 512];
__device__ uint g_dWhh1f[4096 * 512];
__device__ uint g_dOutWf[389 * 512];
__device__ uint g_cOutWf[512 * 512];

// Activation state, packed f16 "T8" layout:
//  u32 index = (k>>3)*128 + b*4 + ((k>>1)&3)   (8 consecutive k per 16B quad)
__device__ uint g_xprev[49 * 128];        // prev, K padded 389->392
__device__ uint g_h0f[2][16384];          // decoder h0 ping-pong (1024 x 32)
__device__ uint g_h1f[2][16384];
__device__ uint g_hc0f[2][16384];         // conductor h ping-pong
__device__ uint g_hc1f[2][16384];
__device__ uint g_embs[8][8192];          // per-subseq emb (512 x 32)

// Tree grid-barrier with fanned-out release (R11-proven).
__device__ uint g_barL[64];        // leaf arrival: 8 blocks each
__device__ uint g_barM[8];         // mid arrival:  8 leaves each
__device__ uint g_barR;            // root arrival: 8 mids
__device__ uint g_relM[8 * 32];    // per-mid release lines (128B stride)
__device__ uint g_relL[64 * 32];   // per-leaf release lines (128B stride)

__device__ __forceinline__ void gridbar(uint e, int bk) {
  __syncthreads();
  if (threadIdx.x == 0) {
    __threadfence();   // device-scope release of this block's stores
    const int lf = bk >> 3, md = bk >> 6;
    uint o = __hip_atomic_fetch_add(&g_barL[lf], 1u,
                                    __ATOMIC_RELAXED, __HIP_MEMORY_SCOPE_AGENT);
    if (o == e * 8u + 7u) {
      o = __hip_atomic_fetch_add(&g_barM[md], 1u,
                                 __ATOMIC_RELAXED, __HIP_MEMORY_SCOPE_AGENT);
      if (o == e * 8u + 7u) {
        o = __hip_atomic_fetch_add(&g_barR, 1u,
                                   __ATOMIC_RELAXED, __HIP_MEMORY_SCOPE_AGENT);
        if (o == e * 8u + 7u) {
#pragma unroll
          for (int m = 0; m < 8; ++m)
            __hip_atomic_store(&g_relM[m << 5], e + 1u, __ATOMIC_RELAXED,
                               __HIP_MEMORY_SCOPE_AGENT);
        }
      }
      while (__hip_atomic_load(&g_relM[md << 5], __ATOMIC_RELAXED,
                               __HIP_MEMORY_SCOPE_AGENT) <= e) {
        __builtin_amdgcn_s_sleep(2);
      }
      __hip_atomic_store(&g_relL[lf << 5], e + 1u, __ATOMIC_RELAXED,
                         __HIP_MEMORY_SCOPE_AGENT);
    } else {
      while (__hip_atomic_load(&g_relL[lf << 5], __ATOMIC_RELAXED,
                               __HIP_MEMORY_SCOPE_AGENT) <= e) {
        __builtin_amdgcn_s_sleep(2);
      }
    }
    __threadfence();   // acquire: invalidate caches before reading new data
  }
  __syncthreads();
}

// PROBE: double barrier. bar_e advances by 2 per call site.
__device__ __forceinline__ void gridbar2(uint& e, int bk) {
  gridbar(e++, bk);
  gridbar(e++, bk);
}

// LDS geometry (u32 units). 60288 bytes total (proven R9/R11).
#define PIH0 200
#define PHH  516
#define OFF_IH0 0
#define OFF_HH0 1600
#define OFF_IH1 5728
#define OFF_HH1 9856
#define OFF_CHH0 0
#define OFF_CIH1 4128
#define OFF_CHH1 8256
#define OFF_PW  13984
#define LDSU32  15072   // 60288 bytes

__device__ __forceinline__ float fast_sig(float x) {
  return 1.0f / (1.0f + __expf(-x));
}
__device__ __forceinline__ float fast_tanh(float x) {
  return 1.0f - 2.0f / (__expf(2.0f * x) + 1.0f);
}

typedef _Float16 half2_t __attribute__((ext_vector_type(2)));

__device__ __forceinline__ float fdot2(uint w, uint x, float acc) {
#if __has_builtin(__builtin_amdgcn_fdot2)
  return __builtin_amdgcn_fdot2(__builtin_bit_cast(half2_t, w),
                                __builtin_bit_cast(half2_t, x), acc, false);
#else
  union { uint u; _Float16 h[2]; } W, X;
  W.u = w; X.u = x;
  acc = fmaf((float)W.h[0], (float)X.h[0], acc);
  return fmaf((float)W.h[1], (float)X.h[1], acc);
#endif
}

__device__ __forceinline__ uint packh2(float lo, float hi) {
  union { uint u; _Float16 h[2]; } r;
  r.h[0] = (_Float16)lo; r.h[1] = (_Float16)hi;
  return r.u;
}

// dot for 2 batches (bE, bE+1) over n chunks of 8 f16.
struct F2 { float e, o; };
__device__ __forceinline__ F2 dot2b(const uint* __restrict__ wp,
                                    const uint* __restrict__ xg,
                                    int n, int bE) {
  float e0=0.f,e1=0.f,e2=0.f,e3=0.f,o0=0.f,o1=0.f,o2=0.f,o3=0.f;
  const uint* xb = xg + (bE << 2);
#pragma unroll 4
  for (int c = 0; c < n; ++c) {
    uint4 w = *(const uint4*)(wp + (c << 2));
    uint4 xe = *(const uint4*)(xb + (c << 7));
    uint4 xo = *(const uint4*)(xb + (c << 7) + 4);
    e0 = fdot2(w.x, xe.x, e0); e1 = fdot2(w.y, xe.y, e1);
    e2 = fdot2(w.z, xe.z, e2); e3 = fdot2(w.w, xe.w, e3);
    o0 = fdot2(w.x, xo.x, o0); o1 = fdot2(w.y, xo.y, o1);
    o2 = fdot2(w.z, xo.z, o2); o3 = fdot2(w.w, xo.w, o3);
  }
  F2 r; r.e = (e0+e1)+(e2+e3); r.o = (o0+o1)+(o2+o3);
  return r;
}

struct KParams {
  const float* latent;
  const float* cWih0; const float* cb0; const float* cb1;
  const float* db0;   const float* db1;
  const float* cOutb; const float* dOutb;
  const float* hdi;   const float* cdi;
  float* out;
};

__global__ __launch_bounds__(NTHR, 2) void decoder_persistent(KParams P) {
  const int tid  = threadIdx.x;
  const int bk   = blockIdx.x;
  const int lane = tid & 63;
  const int b2   = tid >> 4;            // 0..15 -> batches {2*b2, 2*b2+1}
  const int r    = (tid >> 1) & 7;      // row8 = jl*4 + g
  const int kh   = tid & 1;             // ih-side / hh-side
  const int jl   = r >> 2;
  const int g    = r & 3;
  const int j    = bk * 2 + jl;
  const int grow = (g << 10) + j;
  const int bE   = b2 * 2;
  const int pb   = tid >> 3;
  const int ks   = tid & 7;

  uint bar_e = 0;                        // barrier epoch

  __shared__ __align__(16) uint ldsW[LDSU32];

  const float db0v = P.db0[grow];
  const float db1v = P.db1[grow];
  const float cb1v = P.cb1[grow];
  const float coutbv = P.cOutb[bk];
  const float doutbv = (bk < kINP) ? P.dOutb[bk] : 0.f;

  // ---- ihx0 partial: cWih0[grow] . latent[b] (+cb0 on kh=0), K split by kh
  float ihxE, ihxO;
  {
    float a0=0,a1=0,a2=0,a3=0, c0=0,c1=0,c2=0,c3=0;
    const float4* wv = (const float4*)(P.cWih0 + (size_t)grow * kLAT) + kh * 64;
    const float4* xe = (const float4*)(P.latent + (size_t)bE * kLAT) + kh * 64;
    const float4* xo = xe + 128;
#pragma unroll 4
    for (int c = 0; c < 64; ++c) {
      float4 w = wv[c], ve = xe[c], vo = xo[c];
      a0 = fmaf(w.x, ve.x, a0); a1 = fmaf(w.y, ve.y, a1);
      a2 = fmaf(w.z, ve.z, a2); a3 = fmaf(w.w, ve.w, a3);
      c0 = fmaf(w.x, vo.x, c0); c1 = fmaf(w.y, vo.y, c1);
      c2 = fmaf(w.z, vo.z, c2); c3 = fmaf(w.w, vo.w, c3);
    }
    float cb = kh ? 0.f : P.cb0[grow];
    ihxE = (a0+a1)+(a2+a3) + cb;
    ihxO = (c0+c1)+(c2+c3) + cb;
  }

  auto stage = [&](int ldsOff, int pitchL, const uint* src, int srcPitchU32,
                   int cpr) {
    const int total = 8 * cpr;
    for (int idx = tid; idx < total; idx += NTHR) {
      int rr = idx / cpr, c = idx - rr * cpr;
      int gr = ((rr & 3) << 10) + bk * 2 + (rr >> 2);
      uint4 v = *((const uint4*)(src + (size_t)gr * srcPitchU32) + c);
      *(uint4*)&ldsW[ldsOff + rr * pitchL + (c << 2)] = v;
    }
  };

  auto reduce_update = [&](float peE, float peO, float& cEr, float& cOr,
                           uint* dst) {
    float geE = peE + __shfl_xor(peE, 1);
    float geO = peO + __shfl_xor(peO, 1);
    int b8 = lane & ~7;
    float iE = __shfl(geE, b8),     fE = __shfl(geE, b8 + 2);
    float gE = __shfl(geE, b8 + 4), oE = __shfl(geE, b8 + 6);
    float iO = __shfl(geO, b8),     fO = __shfl(geO, b8 + 2);
    float gO = __shfl(geO, b8 + 4), oO = __shfl(geO, b8 + 6);
    float cE = fmaf(fast_sig(fE), cEr, fast_sig(iE) * fast_tanh(gE));
    float cO = fmaf(fast_sig(fO), cOr, fast_sig(iO) * fast_tanh(gO));
    cEr = cE; cOr = cO;
    float hE = fast_sig(oE) * fast_tanh(cE);
    float hO = fast_sig(oO) * fast_tanh(cO);
    float hEx = __shfl(hE, lane ^ 8);
    float hOx = __shfl(hO, lane ^ 8);
    if ((tid & 15) == 0) {
      int idx = (bk >> 2) * 128 + bE * 4 + (bk & 3);
      dst[idx]     = packh2(hE, hEx);
      dst[idx + 4] = packh2(hO, hOx);
    }
  };

  auto proj = [&](int pwOff, float bv, const uint* xbuf,
                  bool active, ushort* dst16, float* outp) {
    float a0=0,a1=0,a2=0,a3=0;
    if (active) {
      const uint* wr = &ldsW[pwOff + ks * 68];
      const uint* xb = xbuf + pb * 4;
#pragma unroll 4
      for (int c = 0; c < 16; ++c) {
        uint4 w = *(const uint4*)(wr + (c << 2));
        uint4 x = *(const uint4*)(xb + ((ks * 16 + c) << 7));
        a0 = fdot2(w.x, x.x, a0); a1 = fdot2(w.y, x.y, a1);
        a2 = fdot2(w.z, x.z, a2); a3 = fdot2(w.w, x.w, a3);
      }
    }
    float v = (a0+a1)+(a2+a3);
    v += __shfl_xor(v, 1); v += __shfl_xor(v, 2); v += __shfl_xor(v, 4);
    if (active && ks == 0) {
      float o = fast_tanh(v + bv);
      dst16[(bk >> 3) * 256 + pb * 8 + (bk & 7)] = (ushort)packh2(o, 0.f);
      if (outp) outp[0] = o;
    }
  };

  // ======================== CONDUCTOR (all 8 steps) ======================
  stage(OFF_CHH0, PHH, g_cWhh0f, 512, 128);
  stage(OFF_CIH1, PHH, g_cWih1f, 512, 128);
  stage(OFF_CHH1, PHH, g_cWhh1f, 512, 128);
  for (int idx = tid; idx < 256; idx += NTHR) {
    int row = idx >> 7, c = idx & 127;
    int dst = OFF_PW + row * 544 + (c >> 4) * 68 + ((c & 15) << 2);
    if (row == 0)
      *(uint4*)&ldsW[dst] = ((const uint4*)(g_cOutWf + (size_t)bk * 512))[c];
    else if (bk < kINP)
      *(uint4*)&ldsW[dst] = ((const uint4*)(g_dOutWf + (size_t)bk * 512))[c];
  }
  __syncthreads();

  float ccE0 = 0.f, ccO0 = 0.f, ccE1 = 0.f, ccO1 = 0.f;
  for (int s = 0; s < kNSUB; ++s) {
    const int p = s & 1;
    {  // conductor L0
      const uint* w1 = &ldsW[OFF_CHH0 + r * PHH + (kh ? 176 : 0)];
      const uint* x1 = g_hc0f[p] + (kh ? 44 * 128 : 0);
      F2 s1 = dot2b(w1, x1, kh ? 42 : 44, bE);
      F2 s2 = dot2b(&ldsW[OFF_CHH0 + r * PHH + 344], g_hc0f[p] + 86 * 128,
                    kh ? 42 : 0, bE);
      reduce_update(ihxE + s1.e + s2.e, ihxO + s1.o + s2.o,
                    ccE0, ccO0, g_hc0f[p ^ 1]);
    }
    gridbar2(bar_e, bk);
    {  // conductor L1
      const int wo = kh ? OFF_CHH1 : OFF_CIH1;
      const uint* xb = kh ? g_hc1f[p] : g_hc0f[p ^ 1];
      F2 s1 = dot2b(&ldsW[wo + r * PHH], xb, 64, bE);
      F2 s2 = dot2b(&ldsW[wo + r * PHH + 256], xb + 64 * 128, 64, bE);
      float cb = kh ? 0.f : cb1v;
      reduce_update(s1.e + s2.e + cb, s1.o + s2.o + cb,
                    ccE1, ccO1, g_hc1f[p ^ 1]);
    }
    gridbar2(bar_e, bk);
    proj(OFF_PW, coutbv, g_hc1f[p ^ 1], true, (ushort*)g_embs[s], nullptr);
    gridbar2(bar_e, bk);
  }

  // ======================== DECODER ======================================
  stage(OFF_IH0, PIH0, g_dWih0f, 456, 49);
  stage(OFF_HH0, PHH,  g_dWhh0f, 512, 128);
  stage(OFF_IH1, PHH,  g_dWih1f, 512, 128);
  stage(OFF_HH1, PHH,  g_dWhh1f, 512, 128);
  __syncthreads();

  for (int s = 0; s < kNSUB; ++s) {
    float cE0 = P.cdi[(((size_t)(s * 2    ) * 32 + bE    )) * 1024 + j];
    float cO0 = P.cdi[(((size_t)(s * 2    ) * 32 + bE + 1)) * 1024 + j];
    float cE1 = P.cdi[(((size_t)(s * 2 + 1) * 32 + bE    )) * 1024 + j];
    float cO1 = P.cdi[(((size_t)(s * 2 + 1) * 32 + bE + 1)) * 1024 + j];
    {
      int gid = bk * NTHR + tid;
      if (gid < 65536) {
        int which = gid >> 15;
        int idx = gid & 32767;
        int jj = idx & 1023, bb = idx >> 10;
        float v = P.hdi[(((size_t)(s * 2 + which) * 32 + bb)) * 1024 + jj];
        ushort* dst = (ushort*)(which ? g_h1f[0] : g_h0f[0]);
        dst[(jj >> 3) * 256 + bb * 8 + (jj & 7)] = (ushort)packh2(v, 0.f);
      }
    }
    F2 ep = dot2b(g_dWih0f + (size_t)grow * 456 + 196 + kh * 128,
                  g_embs[s] + kh * 32 * 128, 32, bE);
    gridbar2(bar_e, bk);

    for (int t = 0; t < kSTEPS; ++t) {
      const int q = t & 1;
      {  // L0
        const uint* w1 = kh ? &ldsW[OFF_HH0 + r * PHH + 160]
                            : &ldsW[OFF_IH0 + r * PIH0];
        const uint* x1 = kh ? g_h0f[q] + 40 * 128 : g_xprev;
        F2 s1 = dot2b(w1, x1, kh ? 44 : 49, bE);
        const uint* w2 = &ldsW[OFF_HH0 + r * PHH + (kh ? 336 : 0)];
        const uint* x2 = g_h0f[q] + (kh ? 84 * 128 : 0);
        F2 s2 = dot2b(w2, x2, kh ? 44 : 40, bE);
        float ex = kh ? 0.f : db0v;
        reduce_update(s1.e + s2.e + ep.e + ex, s1.o + s2.o + ep.o + ex,
                      cE0, cO0, g_h0f[q ^ 1]);
      }
      gridbar2(bar_e, bk);
      {  // L1
        const int wo = kh ? OFF_HH1 : OFF_IH1;
        const uint* xb = kh ? g_h1f[q] : g_h0f[q ^ 1];
        F2 s1 = dot2b(&ldsW[wo + r * PHH], xb, 64, bE);
        F2 s2 = dot2b(&ldsW[wo + r * PHH + 256], xb + 64 * 128, 64, bE);
        float cb = kh ? 0.f : db1v;
        reduce_update(s1.e + s2.e + cb, s1.o + s2.o + cb,
                      cE1, cO1, g_h1f[q ^ 1]);
      }
      gridbar2(bar_e, bk);
      proj(OFF_PW + 544, doutbv, g_h1f[q ^ 1], bk < kINP, (ushort*)g_xprev,
           P.out + (size_t)pb * (kSEQ * kINP) + (size_t)(s * kSTEPS + t) * kINP + bk);
      gridbar2(bar_e, bk);
    }
  }
}

// ---------------------------------------------------------------------------
// Prep: f32 -> f16 weight conversion (+ dWih0 remap), zero state + barrier.
// ---------------------------------------------------------------------------
struct PrepParams {
  const float* cWhh0; const float* cWih1; const float* cWhh1;
  const float* dWih0; const float* dWhh0; const float* dWih1; const float* dWhh1;
  const float* dOutW; const float* cOutW;
};

__device__ __forceinline__ void cvt_mat(const float* __restrict__ src,
                                        uint* __restrict__ dst, int nU32,
                                        int gid0, int gstride) {
  for (int i = gid0; i < nU32; i += gstride) {
    float2 v = ((const float2*)src)[i];
    dst[i] = packh2(v.x, v.y);
  }
}

__global__ void prep_kernel(PrepParams P) {
  int gid0 = blockIdx.x * blockDim.x + threadIdx.x;
  int gs = gridDim.x * blockDim.x;
  cvt_mat(P.cWhh0, g_cWhh0f, 4096 * 512, gid0, gs);
  cvt_mat(P.cWih1, g_cWih1f, 4096 * 512, gid0, gs);
  cvt_mat(P.cWhh1, g_cWhh1f, 4096 * 512, gid0, gs);
  cvt_mat(P.dWhh0, g_dWhh0f, 4096 * 512, gid0, gs);
  cvt_mat(P.dWih1, g_dWih1f, 4096 * 512, gid0, gs);
  cvt_mat(P.dWhh1, g_dWhh1f, 4096 * 512, gid0, gs);
  cvt_mat(P.dOutW, g_dOutWf,  389 * 512, gid0, gs);
  cvt_mat(P.cOutW, g_cOutWf,  512 * 512, gid0, gs);
  for (int i = gid0; i < 4096 * 456; i += gs) {
    int rr = i / 456, c2 = i - rr * 456;
    int c0 = c2 * 2, c1 = c0 + 1;
    const float* row = P.dWih0 + (size_t)rr * 901;
    float v0 = 0.f, v1 = 0.f;
    if (c0 < 389) v0 = row[c0];
    else if (c0 >= 392 && c0 < 904) v0 = row[c0 - 3];
    if (c1 < 389) v1 = row[c1];
    else if (c1 >= 392 && c1 < 904) v1 = row[c1 - 3];
    g_dWih0f[i] = packh2(v0, v1);
  }
  for (int i = gid0; i < 6272; i += gs) g_xprev[i] = 0u;
  for (int i = gid0; i < 16384; i += gs) {
    g_hc0f[0][i] = 0u;
    g_hc1f[0][i] = 0u;
  }
  for (int i = gid0; i < 64; i += gs) g_barL[i] = 0u;
  for (int i = gid0; i < 8; i += gs) g_barM[i] = 0u;
  for (int i = gid0; i < 8 * 32; i += gs) g_relM[i] = 0u;
  for (int i = gid0; i < 64 * 32; i += gs) g_relL[i] = 0u;
  if (gid0 == 0) g_barR = 0u;
}

extern "C" void kernel_launch(void* const* d_in, const int* in_sizes, int n_in,
                              void* d_out, int out_size, void* d_ws, size_t ws_size,
                              hipStream_t stream) {
  const float* latent = (const float*)d_in[0];
  const float* hdi   = (const float*)d_in[2];
  const float* cdi   = (const float*)d_in[3];
  const float* cWih0 = (const float*)d_in[4];
  const float* cWhh0 = (const float*)d_in[5];
  const float* cb0   = (const float*)d_in[6];
  const float* cWih1 = (const float*)d_in[7];
  const float* cWhh1 = (const float*)d_in[8];
  const float* cb1   = (const float*)d_in[9];
  const float* cOutW = (const float*)d_in[10];
  const float* cOutb = (const float*)d_in[11];
  const float* dWih0 = (const float*)d_in[12];
  const float* dWhh0 = (const float*)d_in[13];
  const float* db0   = (const float*)d_in[14];
  const float* dWih1 = (const float*)d_in[15];
  const float* dWhh1 = (const float*)d_in[16];
  const float* db1   = (const float*)d_in[17];
  const float* dOutW = (const float*)d_in[18];
  const float* dOutb = (const float*)d_in[19];
  float* out = (float*)d_out;

  PrepParams pp;
  pp.cWhh0 = cWhh0; pp.cWih1 = cWih1; pp.cWhh1 = cWhh1;
  pp.dWih0 = dWih0; pp.dWhh0 = dWhh0; pp.dWih1 = dWih1; pp.dWhh1 = dWhh1;
  pp.dOutW = dOutW; pp.cOutW = cOutW;
  hipLaunchKernelGGL(prep_kernel, dim3(2048), dim3(256), 0, stream, pp);

  KParams hp;
  hp.latent = latent;
  hp.cWih0 = cWih0; hp.cb0 = cb0; hp.cb1 = cb1;
  hp.db0 = db0; hp.db1 = db1;
  hp.cOutb = cOutb; hp.dOutb = dOutb;
  hp.hdi = hdi; hp.cdi = cdi;
  hp.out = out;

  void* args[] = { &hp };
  hipLaunchCooperativeKernel((void*)decoder_persistent, dim3(NBLK), dim3(NTHR),
                             args, 0, stream);
}

// Round 13
// 17289.670 us; speedup vs baseline: 1.3611x; 1.3611x over previous
//
#include <hip/hip_runtime.h>

// Problem constants
constexpr int kB     = 32;
constexpr int kLAT   = 512;
constexpr int kCH    = 1024;
constexpr int kCO    = 512;
constexpr int kINP   = 389;
constexpr int kH     = 1024;
constexpr int kSEQ   = 128;
constexpr int kNSUB  = 8;
constexpr int kSTEPS = 16;

#define NBLK 512
#define NTHR 256

typedef unsigned long long u64;

// ---------------------------------------------------------------------------
// f16 weight copies (built by prep each launch). Read-only after prep ->
// plain cached loads (cross-kernel boundary flush makes them visible).
// ---------------------------------------------------------------------------
__device__ uint g_cWhh0f[4096 * 512];
__device__ uint g_cWih1f[4096 * 512];
__device__ uint g_cWhh1f[4096 * 512];
__device__ uint g_dWih0f[4096 * 456];
__device__ uint g_dWhh0f[4096 * 512];
__device__ uint g_dWih1f[4096 * 512];
__device__ uint g_dWhh1f[4096 * 512];
__device__ uint g_dOutWf[389 * 512];
__device__ uint g_cOutWf[512 * 512];

// ---------------------------------------------------------------------------
// Cross-phase activation state. Scheme PROVEN by R10 (passed, exact absmax):
// sc1 (agent-scope relaxed) STORES write through to the coherence point and
// keep remote readers consistent; sc1 LOADS read coherently; NO barrier
// fences needed (syncthreads drains vmcnt before the arrival RMW).
// R13 delta vs R10: loads widened u32 -> u64 (half the issue count).
//
// h buffers: packed f16 "T8": u32 idx = (k>>3)*128 + b*4 + ((k>>1)&3).
// prev/emb:  f32 "T4": u32 idx = (k>>2)*128 + b*4 + (k&3) (whole-u32 f32
//            values -- atomic-storable; readers pack f32->f16 RNE, which is
//            bit-identical to storing f16).
// ---------------------------------------------------------------------------
__device__ uint g_xprevF[98 * 128];       // prev f32 T4 (392 x 32, zero-pad)
__device__ uint g_embsF[8][128 * 128];    // per-subseq emb f32 T4 (512 x 32)
__device__ uint g_h0f[2][16384];          // decoder h0 f16 T8 ping-pong
__device__ uint g_h1f[2][16384];
__device__ uint g_hc0f[2][16384];         // conductor h f16 T8 ping-pong
__device__ uint g_hc1f[2][16384];

// ---------------------------------------------------------------------------
// Tree grid-barrier with fanned-out release (R11-proven), MINUS both
// __threadfence()s (fence-free correctness proven by R10's pass; R12
// measured barrier+fences = 17.8us/instance -- this removes the fence part).
// (Do NOT resurrect the R6-R8 flag barrier: bisected fail-zero 3x.)
// ---------------------------------------------------------------------------
__device__ uint g_barL[64];        // leaf arrival: 8 blocks each
__device__ uint g_barM[8];         // mid arrival:  8 leaves each
__device__ uint g_barR;            // root arrival: 8 mids
__device__ uint g_relM[8 * 32];    // per-mid release lines (128B stride)
__device__ uint g_relL[64 * 32];   // per-leaf release lines (128B stride)

__device__ __forceinline__ void gridbar(uint e, int bk) {
  __syncthreads();   // drains vmcnt -> all sc1 stores at coherence point
  if (threadIdx.x == 0) {
    const int lf = bk >> 3, md = bk >> 6;
    uint o = __hip_atomic_fetch_add(&g_barL[lf], 1u,
                                    __ATOMIC_RELAXED, __HIP_MEMORY_SCOPE_AGENT);
    if (o == e * 8u + 7u) {
      o = __hip_atomic_fetch_add(&g_barM[md], 1u,
                                 __ATOMIC_RELAXED, __HIP_MEMORY_SCOPE_AGENT);
      if (o == e * 8u + 7u) {
        o = __hip_atomic_fetch_add(&g_barR, 1u,
                                   __ATOMIC_RELAXED, __HIP_MEMORY_SCOPE_AGENT);
        if (o == e * 8u + 7u) {
#pragma unroll
          for (int m = 0; m < 8; ++m)
            __hip_atomic_store(&g_relM[m << 5], e + 1u, __ATOMIC_RELAXED,
                               __HIP_MEMORY_SCOPE_AGENT);
        }
      }
      while (__hip_atomic_load(&g_relM[md << 5], __ATOMIC_RELAXED,
                               __HIP_MEMORY_SCOPE_AGENT) <= e) {
        __builtin_amdgcn_s_sleep(2);
      }
      __hip_atomic_store(&g_relL[lf << 5], e + 1u, __ATOMIC_RELAXED,
                         __HIP_MEMORY_SCOPE_AGENT);
    } else {
      while (__hip_atomic_load(&g_relL[lf << 5], __ATOMIC_RELAXED,
                               __HIP_MEMORY_SCOPE_AGENT) <= e) {
        __builtin_amdgcn_s_sleep(2);
      }
    }
  }
  __syncthreads();
}

// LDS geometry (u32 units). 60288 bytes (proven R9/R11).
#define PIH0 200
#define PHH  516
#define OFF_IH0 0
#define OFF_HH0 1600
#define OFF_IH1 5728
#define OFF_HH1 9856
#define OFF_CHH0 0
#define OFF_CIH1 4128
#define OFF_CHH1 8256
#define OFF_PW  13984
#define LDSU32  15072   // 60288 bytes

__device__ __forceinline__ float fast_sig(float x) {
  return 1.0f / (1.0f + __expf(-x));
}
__device__ __forceinline__ float fast_tanh(float x) {
  return 1.0f - 2.0f / (__expf(2.0f * x) + 1.0f);
}

typedef _Float16 half2_t __attribute__((ext_vector_type(2)));

__device__ __forceinline__ float fdot2(uint w, uint x, float acc) {
#if __has_builtin(__builtin_amdgcn_fdot2)
  return __builtin_amdgcn_fdot2(__builtin_bit_cast(half2_t, w),
                                __builtin_bit_cast(half2_t, x), acc, false);
#else
  union { uint u; _Float16 h[2]; } W, X;
  W.u = w; X.u = x;
  acc = fmaf((float)W.h[0], (float)X.h[0], acc);
  return fmaf((float)W.h[1], (float)X.h[1], acc);
#endif
}

__device__ __forceinline__ uint packh2(float lo, float hi) {
  union { uint u; _Float16 h[2]; } r;
  r.h[0] = (_Float16)lo; r.h[1] = (_Float16)hi;
  return r.u;
}

// agent-scope relaxed accesses for cross-phase activation data
__device__ __forceinline__ u64 aload64(const u64* p) {
  return __hip_atomic_load(p, __ATOMIC_RELAXED, __HIP_MEMORY_SCOPE_AGENT);
}
__device__ __forceinline__ void astore(uint* p, uint v) {
  __hip_atomic_store(p, v, __ATOMIC_RELAXED, __HIP_MEMORY_SCOPE_AGENT);
}

// pack two consecutive f32 (in one u64) to f16x2 (RNE)
__device__ __forceinline__ uint pk64(u64 q) {
  return packh2(__uint_as_float((uint)q), __uint_as_float((uint)(q >> 32)));
}

struct F2 { float e, o; };

// dot for 2 batches (bE, bE+1) over n chunks of 8 f16; x = f16 T8 buffer,
// sc1 u64 loads. wp: weight row (LDS or global), plain loads.
__device__ __forceinline__ F2 dot2b_s(const uint* __restrict__ wp,
                                      const uint* xg, int n, int bE) {
  float e0=0.f,e1=0.f,e2=0.f,e3=0.f,o0=0.f,o1=0.f,o2=0.f,o3=0.f;
  const uint* xb = xg + (bE << 2);
#pragma unroll 4
  for (int c = 0; c < n; ++c) {
    uint4 w = *(const uint4*)(wp + (c << 2));
    const u64* xc = (const u64*)(xb + (c << 7));
    u64 qe0 = aload64(xc),     qe1 = aload64(xc + 1);
    u64 qo0 = aload64(xc + 2), qo1 = aload64(xc + 3);
    e0 = fdot2(w.x, (uint)qe0, e0); e1 = fdot2(w.y, (uint)(qe0 >> 32), e1);
    e2 = fdot2(w.z, (uint)qe1, e2); e3 = fdot2(w.w, (uint)(qe1 >> 32), e3);
    o0 = fdot2(w.x, (uint)qo0, o0); o1 = fdot2(w.y, (uint)(qo0 >> 32), o1);
    o2 = fdot2(w.z, (uint)qo1, o2); o3 = fdot2(w.w, (uint)(qo1 >> 32), o3);
  }
  F2 r; r.e = (e0+e1)+(e2+e3); r.o = (o0+o1)+(o2+o3);
  return r;
}

// dot for 2 batches over n chunks of 8 k; x = f32 T4 buffer (sc1 u64 loads),
// packed to f16 pairs on the fly (RNE -- identical to storing f16 directly).
__device__ __forceinline__ F2 dot2b_f(const uint* __restrict__ wp,
                                      const uint* xgF, int n, int bE) {
  float e0=0.f,e1=0.f,e2=0.f,e3=0.f,o0=0.f,o1=0.f,o2=0.f,o3=0.f;
  const uint* xb = xgF + (bE << 2);
#pragma unroll 2
  for (int c = 0; c < n; ++c) {
    uint4 w = *(const uint4*)(wp + (c << 2));
    const u64* r0 = (const u64*)(xb + (c << 8));   // T4 row 2c
    const u64* r1 = r0 + 64;                       // T4 row 2c+1
    u64 fe01 = aload64(r0),     fe23 = aload64(r0 + 1);
    u64 fo01 = aload64(r0 + 2), fo23 = aload64(r0 + 3);
    u64 fe45 = aload64(r1),     fe67 = aload64(r1 + 1);
    u64 fo45 = aload64(r1 + 2), fo67 = aload64(r1 + 3);
    e0 = fdot2(w.x, pk64(fe01), e0); e1 = fdot2(w.y, pk64(fe23), e1);
    e2 = fdot2(w.z, pk64(fe45), e2); e3 = fdot2(w.w, pk64(fe67), e3);
    o0 = fdot2(w.x, pk64(fo01), o0); o1 = fdot2(w.y, pk64(fo23), o1);
    o2 = fdot2(w.z, pk64(fo45), o2); o3 = fdot2(w.w, pk64(fo67), o3);
  }
  F2 r; r.e = (e0+e1)+(e2+e3); r.o = (o0+o1)+(o2+o3);
  return r;
}

struct KParams {
  const float* latent;
  const float* cWih0; const float* cb0; const float* cb1;
  const float* db0;   const float* db1;
  const float* cOutb; const float* dOutb;
  const float* hdi;   const float* cdi;
  float* out;
};

__global__ __launch_bounds__(NTHR, 2) void decoder_persistent(KParams P) {
  const int tid  = threadIdx.x;
  const int bk   = blockIdx.x;
  const int lane = tid & 63;
  const int b2   = tid >> 4;            // 0..15 -> batches {2*b2, 2*b2+1}
  const int r    = (tid >> 1) & 7;      // row8 = jl*4 + g
  const int kh   = tid & 1;             // ih-side / hh-side
  const int jl   = r >> 2;
  const int g    = r & 3;
  const int j    = bk * 2 + jl;
  const int grow = (g << 10) + j;
  const int bE   = b2 * 2;
  const int pb   = tid >> 3;
  const int ks   = tid & 7;

  uint bar_e = 0;                        // barrier epoch

  __shared__ __align__(16) uint ldsW[LDSU32];

  const float db0v = P.db0[grow];
  const float db1v = P.db1[grow];
  const float cb1v = P.cb1[grow];
  const float coutbv = P.cOutb[bk];
  const float doutbv = (bk < kINP) ? P.dOutb[bk] : 0.f;

  // ---- ihx0 partial: cWih0[grow] . latent[b] (+cb0 on kh=0), K split by kh
  float ihxE, ihxO;
  {
    float a0=0,a1=0,a2=0,a3=0, c0=0,c1=0,c2=0,c3=0;
    const float4* wv = (const float4*)(P.cWih0 + (size_t)grow * kLAT) + kh * 64;
    const float4* xe = (const float4*)(P.latent + (size_t)bE * kLAT) + kh * 64;
    const float4* xo = xe + 128;
#pragma unroll 4
    for (int c = 0; c < 64; ++c) {
      float4 w = wv[c], ve = xe[c], vo = xo[c];
      a0 = fmaf(w.x, ve.x, a0); a1 = fmaf(w.y, ve.y, a1);
      a2 = fmaf(w.z, ve.z, a2); a3 = fmaf(w.w, ve.w, a3);
      c0 = fmaf(w.x, vo.x, c0); c1 = fmaf(w.y, vo.y, c1);
      c2 = fmaf(w.z, vo.z, c2); c3 = fmaf(w.w, vo.w, c3);
    }
    float cb = kh ? 0.f : P.cb0[grow];
    ihxE = (a0+a1)+(a2+a3) + cb;
    ihxO = (c0+c1)+(c2+c3) + cb;
  }

  auto stage = [&](int ldsOff, int pitchL, const uint* src, int srcPitchU32,
                   int cpr) {
    const int total = 8 * cpr;
    for (int idx = tid; idx < total; idx += NTHR) {
      int rr = idx / cpr, c = idx - rr * cpr;
      int gr = ((rr & 3) << 10) + bk * 2 + (rr >> 2);
      uint4 v = *((const uint4*)(src + (size_t)gr * srcPitchU32) + c);
      *(uint4*)&ldsW[ldsOff + rr * pitchL + (c << 2)] = v;
    }
  };

  auto reduce_update = [&](float peE, float peO, float& cEr, float& cOr,
                           uint* dst) {
    float geE = peE + __shfl_xor(peE, 1);
    float geO = peO + __shfl_xor(peO, 1);
    int b8 = lane & ~7;
    float iE = __shfl(geE, b8),     fE = __shfl(geE, b8 + 2);
    float gE = __shfl(geE, b8 + 4), oE = __shfl(geE, b8 + 6);
    float iO = __shfl(geO, b8),     fO = __shfl(geO, b8 + 2);
    float gO = __shfl(geO, b8 + 4), oO = __shfl(geO, b8 + 6);
    float cE = fmaf(fast_sig(fE), cEr, fast_sig(iE) * fast_tanh(gE));
    float cO = fmaf(fast_sig(fO), cOr, fast_sig(iO) * fast_tanh(gO));
    cEr = cE; cOr = cO;
    float hE = fast_sig(oE) * fast_tanh(cE);
    float hO = fast_sig(oO) * fast_tanh(cO);
    float hEx = __shfl(hE, lane ^ 8);
    float hOx = __shfl(hO, lane ^ 8);
    if ((tid & 15) == 0) {
      int idx = (bk >> 2) * 128 + bE * 4 + (bk & 3);
      astore(&dst[idx],     packh2(hE, hEx));
      astore(&dst[idx + 4], packh2(hO, hOx));
    }
  };

  // proj: weights in LDS; x = f16 T8 via sc1 u64; result -> f32 T4 (sc1) +
  // optional plain store to out (host reads after kernel end).
  auto proj = [&](int pwOff, float bv, const uint* xbuf,
                  bool active, uint* dstF, float* outp) {
    float a0=0,a1=0,a2=0,a3=0;
    if (active) {
      const uint* wr = &ldsW[pwOff + ks * 68];
      const uint* xb = xbuf + pb * 4;
#pragma unroll 4
      for (int c = 0; c < 16; ++c) {
        uint4 w = *(const uint4*)(wr + (c << 2));
        const u64* xc = (const u64*)(xb + ((ks * 16 + c) << 7));
        u64 xa = aload64(xc), xq = aload64(xc + 1);
        a0 = fdot2(w.x, (uint)xa, a0); a1 = fdot2(w.y, (uint)(xa >> 32), a1);
        a2 = fdot2(w.z, (uint)xq, a2); a3 = fdot2(w.w, (uint)(xq >> 32), a3);
      }
    }
    float v = (a0+a1)+(a2+a3);
    v += __shfl_xor(v, 1); v += __shfl_xor(v, 2); v += __shfl_xor(v, 4);
    if (active && ks == 0) {
      float o = fast_tanh(v + bv);
      astore(dstF + pb * 4, __float_as_uint(o));
      if (outp) outp[0] = o;
    }
  };

  // ======================== CONDUCTOR (all 8 steps) ======================
  stage(OFF_CHH0, PHH, g_cWhh0f, 512, 128);
  stage(OFF_CIH1, PHH, g_cWih1f, 512, 128);
  stage(OFF_CHH1, PHH, g_cWhh1f, 512, 128);
  for (int idx = tid; idx < 256; idx += NTHR) {
    int row = idx >> 7, c = idx & 127;
    int dst = OFF_PW + row * 544 + (c >> 4) * 68 + ((c & 15) << 2);
    if (row == 0)
      *(uint4*)&ldsW[dst] = ((const uint4*)(g_cOutWf + (size_t)bk * 512))[c];
    else if (bk < kINP)
      *(uint4*)&ldsW[dst] = ((const uint4*)(g_dOutWf + (size_t)bk * 512))[c];
  }
  __syncthreads();

  float ccE0 = 0.f, ccO0 = 0.f, ccE1 = 0.f, ccO1 = 0.f;
  for (int s = 0; s < kNSUB; ++s) {
    const int p = s & 1;
    {  // conductor L0: kh0 = ihx0 only; hh split 44/42/42
      const uint* w1 = &ldsW[OFF_CHH0 + r * PHH + (kh ? 176 : 0)];
      const uint* x1 = g_hc0f[p] + (kh ? 44 * 128 : 0);
      F2 s1 = dot2b_s(w1, x1, kh ? 42 : 44, bE);
      F2 s2 = dot2b_s(&ldsW[OFF_CHH0 + r * PHH + 344], g_hc0f[p] + 86 * 128,
                      kh ? 42 : 0, bE);
      reduce_update(ihxE + s1.e + s2.e, ihxO + s1.o + s2.o,
                    ccE0, ccO0, g_hc0f[p ^ 1]);
    }
    gridbar(bar_e++, bk);
    {  // conductor L1: kh0 = ih(hc0new), kh1 = hh(hc1 old); 64+64
      const int wo = kh ? OFF_CHH1 : OFF_CIH1;
      const uint* xb = kh ? g_hc1f[p] : g_hc0f[p ^ 1];
      F2 s1 = dot2b_s(&ldsW[wo + r * PHH], xb, 64, bE);
      F2 s2 = dot2b_s(&ldsW[wo + r * PHH + 256], xb + 64 * 128, 64, bE);
      float cb = kh ? 0.f : cb1v;
      reduce_update(s1.e + s2.e + cb, s1.o + s2.o + cb,
                    ccE1, ccO1, g_hc1f[p ^ 1]);
    }
    gridbar(bar_e++, bk);
    proj(OFF_PW, coutbv, g_hc1f[p ^ 1], true,
         g_embsF[s] + (bk >> 2) * 128 + (bk & 3), nullptr);
    gridbar(bar_e++, bk);
  }

  // ======================== DECODER ======================================
  stage(OFF_IH0, PIH0, g_dWih0f, 456, 49);   // prev-part only (196 u32/row)
  stage(OFF_HH0, PHH,  g_dWhh0f, 512, 128);
  stage(OFF_IH1, PHH,  g_dWih1f, 512, 128);
  stage(OFF_HH1, PHH,  g_dWhh1f, 512, 128);
  __syncthreads();

  for (int s = 0; s < kNSUB; ++s) {
    float cE0 = P.cdi[(((size_t)(s * 2    ) * 32 + bE    )) * 1024 + j];
    float cO0 = P.cdi[(((size_t)(s * 2    ) * 32 + bE + 1)) * 1024 + j];
    float cE1 = P.cdi[(((size_t)(s * 2 + 1) * 32 + bE    )) * 1024 + j];
    float cO1 = P.cdi[(((size_t)(s * 2 + 1) * 32 + bE + 1)) * 1024 + j];
    {
      // h-state init: one u32 (2 adjacent channels) per task -> sc1-storable
      int gid = bk * NTHR + tid;
      if (gid < 32768) {
        int which = gid >> 14;           // 0: h0, 1: h1
        int idx = gid & 16383;
        int jp = idx & 511, bb = idx >> 9;
        int jj = jp * 2;
        const float* src =
            P.hdi + (((size_t)(s * 2 + which)) * 32 + bb) * 1024 + jj;
        uint* dst = which ? g_h1f[0] : g_h0f[0];
        astore(&dst[(jp >> 2) * 128 + bb * 4 + (jp & 3)],
               packh2(src[0], src[1]));
      }
    }
    // emb-part of L0 ih dot: weights global (plain), emb f32 T4 via sc1
    F2 ep = dot2b_f(g_dWih0f + (size_t)grow * 456 + 196 + kh * 128,
                    g_embsF[s] + kh * 64 * 128, 32, bE);
    gridbar(bar_e++, bk);

    for (int t = 0; t < kSTEPS; ++t) {
      const int q = t & 1;
      {  // L0: kh0 = prev(49 f32-chunks) + hh[0:40); kh1 = hh[40:84)+[84:128)
        F2 s1 = kh ? dot2b_s(&ldsW[OFF_HH0 + r * PHH + 160],
                             g_h0f[q] + 40 * 128, 44, bE)
                   : dot2b_f(&ldsW[OFF_IH0 + r * PIH0], g_xprevF, 49, bE);
        const uint* w2 = &ldsW[OFF_HH0 + r * PHH + (kh ? 336 : 0)];
        const uint* x2 = g_h0f[q] + (kh ? 84 * 128 : 0);
        F2 s2 = dot2b_s(w2, x2, kh ? 44 : 40, bE);
        float ex = kh ? 0.f : db0v;
        reduce_update(s1.e + s2.e + ep.e + ex, s1.o + s2.o + ep.o + ex,
                      cE0, cO0, g_h0f[q ^ 1]);
      }
      gridbar(bar_e++, bk);
      {  // L1: kh0 = ih(h0new), kh1 = hh(h1 old)
        const int wo = kh ? OFF_HH1 : OFF_IH1;
        const uint* xb = kh ? g_h1f[q] : g_h0f[q ^ 1];
        F2 s1 = dot2b_s(&ldsW[wo + r * PHH], xb, 64, bE);
        F2 s2 = dot2b_s(&ldsW[wo + r * PHH + 256], xb + 64 * 128, 64, bE);
        float cb = kh ? 0.f : db1v;
        reduce_update(s1.e + s2.e + cb, s1.o + s2.o + cb,
                      cE1, cO1, g_h1f[q ^ 1]);
      }
      gridbar(bar_e++, bk);
      proj(OFF_PW + 544, doutbv, g_h1f[q ^ 1], bk < kINP,
           g_xprevF + (bk >> 2) * 128 + (bk & 3),
           P.out + (size_t)pb * (kSEQ * kINP) + (size_t)(s * kSTEPS + t) * kINP + bk);
      gridbar(bar_e++, bk);
    }
  }
}

// ---------------------------------------------------------------------------
// Prep: f32 -> f16 weight conversion (+ dWih0 remap), zero state + barrier.
// ---------------------------------------------------------------------------
struct PrepParams {
  const float* cWhh0; const float* cWih1; const float* cWhh1;
  const float* dWih0; const float* dWhh0; const float* dWih1; const float* dWhh1;
  const float* dOutW; const float* cOutW;
};

__device__ __forceinline__ void cvt_mat(const float* __restrict__ src,
                                        uint* __restrict__ dst, int nU32,
                                        int gid0, int gstride) {
  for (int i = gid0; i < nU32; i += gstride) {
    float2 v = ((const float2*)src)[i];
    dst[i] = packh2(v.x, v.y);
  }
}

__global__ void prep_kernel(PrepParams P) {
  int gid0 = blockIdx.x * blockDim.x + threadIdx.x;
  int gs = gridDim.x * blockDim.x;
  cvt_mat(P.cWhh0, g_cWhh0f, 4096 * 512, gid0, gs);
  cvt_mat(P.cWih1, g_cWih1f, 4096 * 512, gid0, gs);
  cvt_mat(P.cWhh1, g_cWhh1f, 4096 * 512, gid0, gs);
  cvt_mat(P.dWhh0, g_dWhh0f, 4096 * 512, gid0, gs);
  cvt_mat(P.dWih1, g_dWih1f, 4096 * 512, gid0, gs);
  cvt_mat(P.dWhh1, g_dWhh1f, 4096 * 512, gid0, gs);
  cvt_mat(P.dOutW, g_dOutWf,  389 * 512, gid0, gs);
  cvt_mat(P.cOutW, g_cOutWf,  512 * 512, gid0, gs);
  // dWih0 remap: f16 col layout [0..388 prev][389..391 z][392..903 emb][pad]
  for (int i = gid0; i < 4096 * 456; i += gs) {
    int rr = i / 456, c2 = i - rr * 456;
    int c0 = c2 * 2, c1 = c0 + 1;
    const float* row = P.dWih0 + (size_t)rr * 901;
    float v0 = 0.f, v1 = 0.f;
    if (c0 < 389) v0 = row[c0];
    else if (c0 >= 392 && c0 < 904) v0 = row[c0 - 3];
    if (c1 < 389) v1 = row[c1];
    else if (c1 >= 392 && c1 < 904) v1 = row[c1 - 3];
    g_dWih0f[i] = packh2(v0, v1);
  }
  // zero initial states
  for (int i = gid0; i < 98 * 128; i += gs) g_xprevF[i] = 0u;
  for (int i = gid0; i < 16384; i += gs) {
    g_hc0f[0][i] = 0u;
    g_hc1f[0][i] = 0u;
  }
  // zero barrier state (every launch -> deterministic graph replays)
  for (int i = gid0; i < 64; i += gs) g_barL[i] = 0u;
  for (int i = gid0; i < 8; i += gs) g_barM[i] = 0u;
  for (int i = gid0; i < 8 * 32; i += gs) g_relM[i] = 0u;
  for (int i = gid0; i < 64 * 32; i += gs) g_relL[i] = 0u;
  if (gid0 == 0) g_barR = 0u;
}

extern "C" void kernel_launch(void* const* d_in, const int* in_sizes, int n_in,
                              void* d_out, int out_size, void* d_ws, size_t ws_size,
                              hipStream_t stream) {
  const float* latent = (const float*)d_in[0];
  const float* hdi   = (const float*)d_in[2];
  const float* cdi   = (const float*)d_in[3];
  const float* cWih0 = (const float*)d_in[4];
  const float* cWhh0 = (const float*)d_in[5];
  const float* cb0   = (const float*)d_in[6];
  const float* cWih1 = (const float*)d_in[7];
  const float* cWhh1 = (const float*)d_in[8];
  const float* cb1   = (const float*)d_in[9];
  const float* cOutW = (const float*)d_in[10];
  const float* cOutb = (const float*)d_in[11];
  const float* dWih0 = (const float*)d_in[12];
  const float* dWhh0 = (const float*)d_in[13];
  const float* db0   = (const float*)d_in[14];
  const float* dWih1 = (const float*)d_in[15];
  const float* dWhh1 = (const float*)d_in[16];
  const float* db1   = (const float*)d_in[17];
  const float* dOutW = (const float*)d_in[18];
  const float* dOutb = (const float*)d_in[19];
  float* out = (float*)d_out;

  PrepParams pp;
  pp.cWhh0 = cWhh0; pp.cWih1 = cWih1; pp.cWhh1 = cWhh1;
  pp.dWih0 = dWih0; pp.dWhh0 = dWhh0; pp.dWih1 = dWih1; pp.dWhh1 = dWhh1;
  pp.dOutW = dOutW; pp.cOutW = cOutW;
  hipLaunchKernelGGL(prep_kernel, dim3(2048), dim3(256), 0, stream, pp);

  KParams hp;
  hp.latent = latent;
  hp.cWih0 = cWih0; hp.cb0 = cb0; hp.cb1 = cb1;
  hp.db0 = db0; hp.db1 = db1;
  hp.cOutb = cOutb; hp.dOutb = dOutb;
  hp.hdi = hdi; hp.cdi = cdi;
  hp.out = out;

  void* args[] = { &hp };
  hipLaunchCooperativeKernel((void*)decoder_persistent, dim3(NBLK), dim3(NTHR),
                             args, 0, stream);
}

// Round 15
// 12984.428 us; speedup vs baseline: 1.8125x; 1.3316x over previous
//
#include <hip/hip_runtime.h>

// Problem constants
constexpr int kB     = 32;
constexpr int kLAT   = 512;
constexpr int kCH    = 1024;
constexpr int kCO    = 512;
constexpr int kINP   = 389;
constexpr int kH     = 1024;
constexpr int kSEQ   = 128;
constexpr int kNSUB  = 8;
constexpr int kSTEPS = 16;

#define NBLK 512
#define NTHR 256   // PROVEN launch shape (R9/R11/R13). Do not change blindly:
                   // every launch-shape delta so far (R6,R7,R8,R14) fail-zeroed.

// ---------------------------------------------------------------------------
// f16 weight copies (prep each launch). Read-only -> plain cached loads.
// ---------------------------------------------------------------------------
__device__ uint g_cWhh0f[4096 * 512];
__device__ uint g_cWih1f[4096 * 512];
__device__ uint g_cWhh1f[4096 * 512];
__device__ uint g_dWih0f[4096 * 456];
__device__ uint g_dWhh0f[4096 * 512];
__device__ uint g_dWih1f[4096 * 512];
__device__ uint g_dWhh1f[4096 * 512];
__device__ uint g_dOutWf[389 * 512];
__device__ uint g_cOutWf[512 * 512];

// ---------------------------------------------------------------------------
// Cross-phase activations. COHERENCE SCHEME (each piece separately proven):
//  - STORES: sc1 agent-scope relaxed u32 (write-through)  [R10/R13 PASS]
//  - LOADS:  plain uint4 (vectorized, L2-cacheable)       [R11 PASS]
//  - gridbar keeps ONLY the acquire __threadfence (L2 inv) so plain loads
//    never see stale lines; the release fence is deleted (sc1 stores are at
//    the coherence point once __syncthreads drains vmcnt -- R10/R13 passed
//    with NO fences at all). R12 measured the fence pair ~15us/barrier
//    (fixed L2 tag-walk cost) -- this halves it.
// h buffers: f16 "T8": u32 idx=(k>>3)*128 + b*4 + ((k>>1)&3).
// prev/emb:  f32 "T4": u32 idx=(k>>2)*128 + b*4 + (k&3) (atomic-storable;
//            readers pack f32->f16 RNE = bit-identical to storing f16).
// ---------------------------------------------------------------------------
__device__ uint g_xprevF[98 * 128];       // prev f32 T4 (392 x 32, zero-pad)
__device__ uint g_embsF[8][128 * 128];    // per-subseq emb f32 T4 (512 x 32)
__device__ uint g_h0f[2][16384];          // decoder h0 f16 T8 ping-pong
__device__ uint g_h1f[2][16384];
__device__ uint g_hc0f[2][16384];         // conductor h f16 T8 ping-pong
__device__ uint g_hc1f[2][16384];

// ---------------------------------------------------------------------------
// Tree grid-barrier, arrival + fanned-out release (R11-proven), with the
// release __threadfence removed and the acquire __threadfence kept.
// (R6-R8 flag barrier: fail-zeroed 3x, bisected -- do not resurrect.)
// ---------------------------------------------------------------------------
__device__ uint g_barL[64];        // leaf arrival: 8 blocks each
__device__ uint g_barM[8];         // mid arrival:  8 leaves each
__device__ uint g_barR;            // root arrival: 8 mids
__device__ uint g_relM[8 * 32];    // per-mid release lines (128B stride)
__device__ uint g_relL[64 * 32];   // per-leaf release lines (128B stride)

__device__ __forceinline__ void gridbar(uint e, int bk) {
  __syncthreads();   // drains vmcnt -> sc1 stores at coherence point
  if (threadIdx.x == 0) {
    const int lf = bk >> 3, md = bk >> 6;
    uint o = __hip_atomic_fetch_add(&g_barL[lf], 1u,
                                    __ATOMIC_RELAXED, __HIP_MEMORY_SCOPE_AGENT);
    if (o == e * 8u + 7u) {
      o = __hip_atomic_fetch_add(&g_barM[md], 1u,
                                 __ATOMIC_RELAXED, __HIP_MEMORY_SCOPE_AGENT);
      if (o == e * 8u + 7u) {
        o = __hip_atomic_fetch_add(&g_barR, 1u,
                                   __ATOMIC_RELAXED, __HIP_MEMORY_SCOPE_AGENT);
        if (o == e * 8u + 7u) {
#pragma unroll
          for (int m = 0; m < 8; ++m)
            __hip_atomic_store(&g_relM[m << 5], e + 1u, __ATOMIC_RELAXED,
                               __HIP_MEMORY_SCOPE_AGENT);
        }
      }
      while (__hip_atomic_load(&g_relM[md << 5], __ATOMIC_RELAXED,
                               __HIP_MEMORY_SCOPE_AGENT) <= e) {
        __builtin_amdgcn_s_sleep(2);
      }
      __hip_atomic_store(&g_relL[lf << 5], e + 1u, __ATOMIC_RELAXED,
                         __HIP_MEMORY_SCOPE_AGENT);
    } else {
      while (__hip_atomic_load(&g_relL[lf << 5], __ATOMIC_RELAXED,
                               __HIP_MEMORY_SCOPE_AGENT) <= e) {
        __builtin_amdgcn_s_sleep(2);
      }
    }
    __threadfence();   // ACQUIRE only: invalidate L1/L2 for the plain loads
  }
  __syncthreads();
}

// LDS geometry (u32 units). 60288 bytes (proven R9/R11/R13).
#define PIH0 200
#define PHH  516
#define OFF_IH0 0
#define OFF_HH0 1600
#define OFF_IH1 5728
#define OFF_HH1 9856
#define OFF_CHH0 0
#define OFF_CIH1 4128
#define OFF_CHH1 8256
#define OFF_PW  13984
#define LDSU32  15072   // 60288 bytes

__device__ __forceinline__ float fast_sig(float x) {
  return 1.0f / (1.0f + __expf(-x));
}
__device__ __forceinline__ float fast_tanh(float x) {
  return 1.0f - 2.0f / (__expf(2.0f * x) + 1.0f);
}

typedef _Float16 half2_t __attribute__((ext_vector_type(2)));

__device__ __forceinline__ float fdot2(uint w, uint x, float acc) {
#if __has_builtin(__builtin_amdgcn_fdot2)
  return __builtin_amdgcn_fdot2(__builtin_bit_cast(half2_t, w),
                                __builtin_bit_cast(half2_t, x), acc, false);
#else
  union { uint u; _Float16 h[2]; } W, X;
  W.u = w; X.u = x;
  acc = fmaf((float)W.h[0], (float)X.h[0], acc);
  return fmaf((float)W.h[1], (float)X.h[1], acc);
#endif
}

__device__ __forceinline__ uint packh2(float lo, float hi) {
  union { uint u; _Float16 h[2]; } r;
  r.h[0] = (_Float16)lo; r.h[1] = (_Float16)hi;
  return r.u;
}

// sc1 store for cross-phase activation data (proven R10/R13)
__device__ __forceinline__ void astore(uint* p, uint v) {
  __hip_atomic_store(p, v, __ATOMIC_RELAXED, __HIP_MEMORY_SCOPE_AGENT);
}

struct F2 { float e, o; };

// dot for 2 batches (bE, bE+1) over n chunks of 8 f16; x = f16 T8 buffer,
// PLAIN uint4 loads (R11-proven). wp: weight row (LDS or global).
__device__ __forceinline__ F2 dot2b(const uint* __restrict__ wp,
                                    const uint* __restrict__ xg,
                                    int n, int bE) {
  float e0=0.f,e1=0.f,e2=0.f,e3=0.f,o0=0.f,o1=0.f,o2=0.f,o3=0.f;
  const uint* xb = xg + (bE << 2);
#pragma unroll 4
  for (int c = 0; c < n; ++c) {
    uint4 w = *(const uint4*)(wp + (c << 2));
    uint4 xe = *(const uint4*)(xb + (c << 7));
    uint4 xo = *(const uint4*)(xb + (c << 7) + 4);
    e0 = fdot2(w.x, xe.x, e0); e1 = fdot2(w.y, xe.y, e1);
    e2 = fdot2(w.z, xe.z, e2); e3 = fdot2(w.w, xe.w, e3);
    o0 = fdot2(w.x, xo.x, o0); o1 = fdot2(w.y, xo.y, o1);
    o2 = fdot2(w.z, xo.z, o2); o3 = fdot2(w.w, xo.w, o3);
  }
  F2 r; r.e = (e0+e1)+(e2+e3); r.o = (o0+o1)+(o2+o3);
  return r;
}

// dot for 2 batches over n chunks of 8 k; x = f32 T4 buffer, PLAIN uint4
// loads, packed to f16 pairs on the fly (RNE - identical to storing f16).
__device__ __forceinline__ F2 dot2b_f(const uint* __restrict__ wp,
                                      const uint* __restrict__ xgF,
                                      int n, int bE) {
  float e0=0.f,e1=0.f,e2=0.f,e3=0.f,o0=0.f,o1=0.f,o2=0.f,o3=0.f;
  const uint* xb = xgF + (bE << 2);
#pragma unroll 2
  for (int c = 0; c < n; ++c) {
    uint4 w = *(const uint4*)(wp + (c << 2));
    const uint* r0 = xb + (c << 8);        // T4 row 2c: k=8c..8c+3
    const uint* r1 = r0 + 128;             // row 2c+1:  k=8c+4..8c+7
    uint4 xe0 = *(const uint4*)(r0);       // even batch
    uint4 xe1 = *(const uint4*)(r1);
    uint4 xo0 = *(const uint4*)(r0 + 4);   // odd batch
    uint4 xo1 = *(const uint4*)(r1 + 4);
    e0 = fdot2(w.x, packh2(__uint_as_float(xe0.x), __uint_as_float(xe0.y)), e0);
    e1 = fdot2(w.y, packh2(__uint_as_float(xe0.z), __uint_as_float(xe0.w)), e1);
    e2 = fdot2(w.z, packh2(__uint_as_float(xe1.x), __uint_as_float(xe1.y)), e2);
    e3 = fdot2(w.w, packh2(__uint_as_float(xe1.z), __uint_as_float(xe1.w)), e3);
    o0 = fdot2(w.x, packh2(__uint_as_float(xo0.x), __uint_as_float(xo0.y)), o0);
    o1 = fdot2(w.y, packh2(__uint_as_float(xo0.z), __uint_as_float(xo0.w)), o1);
    o2 = fdot2(w.z, packh2(__uint_as_float(xo1.x), __uint_as_float(xo1.y)), o2);
    o3 = fdot2(w.w, packh2(__uint_as_float(xo1.z), __uint_as_float(xo1.w)), o3);
  }
  F2 r; r.e = (e0+e1)+(e2+e3); r.o = (o0+o1)+(o2+o3);
  return r;
}

struct KParams {
  const float* latent;
  const float* cWih0; const float* cb0; const float* cb1;
  const float* db0;   const float* db1;
  const float* cOutb; const float* dOutb;
  const float* hdi;   const float* cdi;
  float* out;
};

__global__ __launch_bounds__(NTHR, 2) void decoder_persistent(KParams P) {
  const int tid  = threadIdx.x;
  const int bk   = blockIdx.x;
  const int lane = tid & 63;
  const int b2   = tid >> 4;            // 0..15 -> batches {2*b2, 2*b2+1}
  const int r    = (tid >> 1) & 7;      // row8 = jl*4 + g
  const int kh   = tid & 1;             // ih-side / hh-side
  const int jl   = r >> 2;
  const int g    = r & 3;
  const int j    = bk * 2 + jl;
  const int grow = (g << 10) + j;
  const int bE   = b2 * 2;
  const int pb   = tid >> 3;
  const int ks   = tid & 7;

  uint bar_e = 0;                        // barrier epoch

  __shared__ __align__(16) uint ldsW[LDSU32];

  const float db0v = P.db0[grow];
  const float db1v = P.db1[grow];
  const float cb1v = P.cb1[grow];
  const float coutbv = P.cOutb[bk];
  const float doutbv = (bk < kINP) ? P.dOutb[bk] : 0.f;

  // ---- ihx0 partial: cWih0[grow] . latent[b] (+cb0 on kh=0), K split by kh
  float ihxE, ihxO;
  {
    float a0=0,a1=0,a2=0,a3=0, c0=0,c1=0,c2=0,c3=0;
    const float4* wv = (const float4*)(P.cWih0 + (size_t)grow * kLAT) + kh * 64;
    const float4* xe = (const float4*)(P.latent + (size_t)bE * kLAT) + kh * 64;
    const float4* xo = xe + 128;
#pragma unroll 4
    for (int c = 0; c < 64; ++c) {
      float4 w = wv[c], ve = xe[c], vo = xo[c];
      a0 = fmaf(w.x, ve.x, a0); a1 = fmaf(w.y, ve.y, a1);
      a2 = fmaf(w.z, ve.z, a2); a3 = fmaf(w.w, ve.w, a3);
      c0 = fmaf(w.x, vo.x, c0); c1 = fmaf(w.y, vo.y, c1);
      c2 = fmaf(w.z, vo.z, c2); c3 = fmaf(w.w, vo.w, c3);
    }
    float cb = kh ? 0.f : P.cb0[grow];
    ihxE = (a0+a1)+(a2+a3) + cb;
    ihxO = (c0+c1)+(c2+c3) + cb;
  }

  auto stage = [&](int ldsOff, int pitchL, const uint* src, int srcPitchU32,
                   int cpr) {
    const int total = 8 * cpr;
    for (int idx = tid; idx < total; idx += NTHR) {
      int rr = idx / cpr, c = idx - rr * cpr;
      int gr = ((rr & 3) << 10) + bk * 2 + (rr >> 2);
      uint4 v = *((const uint4*)(src + (size_t)gr * srcPitchU32) + c);
      *(uint4*)&ldsW[ldsOff + rr * pitchL + (c << 2)] = v;
    }
  };

  auto reduce_update = [&](float peE, float peO, float& cEr, float& cOr,
                           uint* dst) {
    float geE = peE + __shfl_xor(peE, 1);
    float geO = peO + __shfl_xor(peO, 1);
    int b8 = lane & ~7;
    float iE = __shfl(geE, b8),     fE = __shfl(geE, b8 + 2);
    float gE = __shfl(geE, b8 + 4), oE = __shfl(geE, b8 + 6);
    float iO = __shfl(geO, b8),     fO = __shfl(geO, b8 + 2);
    float gO = __shfl(geO, b8 + 4), oO = __shfl(geO, b8 + 6);
    float cE = fmaf(fast_sig(fE), cEr, fast_sig(iE) * fast_tanh(gE));
    float cO = fmaf(fast_sig(fO), cOr, fast_sig(iO) * fast_tanh(gO));
    cEr = cE; cOr = cO;
    float hE = fast_sig(oE) * fast_tanh(cE);
    float hO = fast_sig(oO) * fast_tanh(cO);
    float hEx = __shfl(hE, lane ^ 8);
    float hOx = __shfl(hO, lane ^ 8);
    if ((tid & 15) == 0) {
      int idx = (bk >> 2) * 128 + bE * 4 + (bk & 3);
      astore(&dst[idx],     packh2(hE, hEx));
      astore(&dst[idx + 4], packh2(hO, hOx));
    }
  };

  // proj: weights in LDS; x = f16 T8 plain uint4; result -> f32 T4 via sc1
  // + optional plain store to out (host reads after kernel end).
  auto proj = [&](int pwOff, float bv, const uint* xbuf,
                  bool active, uint* dstF, float* outp) {
    float a0=0,a1=0,a2=0,a3=0;
    if (active) {
      const uint* wr = &ldsW[pwOff + ks * 68];
      const uint* xb = xbuf + pb * 4;
#pragma unroll 4
      for (int c = 0; c < 16; ++c) {
        uint4 w = *(const uint4*)(wr + (c << 2));
        uint4 x = *(const uint4*)(xb + ((ks * 16 + c) << 7));
        a0 = fdot2(w.x, x.x, a0); a1 = fdot2(w.y, x.y, a1);
        a2 = fdot2(w.z, x.z, a2); a3 = fdot2(w.w, x.w, a3);
      }
    }
    float v = (a0+a1)+(a2+a3);
    v += __shfl_xor(v, 1); v += __shfl_xor(v, 2); v += __shfl_xor(v, 4);
    if (active && ks == 0) {
      float o = fast_tanh(v + bv);
      astore(dstF + pb * 4, __float_as_uint(o));
      if (outp) outp[0] = o;
    }
  };

  // ======================== CONDUCTOR (all 8 steps) ======================
  stage(OFF_CHH0, PHH, g_cWhh0f, 512, 128);
  stage(OFF_CIH1, PHH, g_cWih1f, 512, 128);
  stage(OFF_CHH1, PHH, g_cWhh1f, 512, 128);
  for (int idx = tid; idx < 256; idx += NTHR) {
    int row = idx >> 7, c = idx & 127;
    int dst = OFF_PW + row * 544 + (c >> 4) * 68 + ((c & 15) << 2);
    if (row == 0)
      *(uint4*)&ldsW[dst] = ((const uint4*)(g_cOutWf + (size_t)bk * 512))[c];
    else if (bk < kINP)
      *(uint4*)&ldsW[dst] = ((const uint4*)(g_dOutWf + (size_t)bk * 512))[c];
  }
  __syncthreads();

  float ccE0 = 0.f, ccO0 = 0.f, ccE1 = 0.f, ccO1 = 0.f;
  for (int s = 0; s < kNSUB; ++s) {
    const int p = s & 1;
    {  // conductor L0: kh0 = ihx0 + hh[0:44); kh1 = hh[44:86) + hh[86:128)
      const uint* w1 = &ldsW[OFF_CHH0 + r * PHH + (kh ? 176 : 0)];
      const uint* x1 = g_hc0f[p] + (kh ? 44 * 128 : 0);
      F2 s1 = dot2b(w1, x1, kh ? 42 : 44, bE);
      F2 s2 = dot2b(&ldsW[OFF_CHH0 + r * PHH + 344], g_hc0f[p] + 86 * 128,
                    kh ? 42 : 0, bE);
      reduce_update(ihxE + s1.e + s2.e, ihxO + s1.o + s2.o,
                    ccE0, ccO0, g_hc0f[p ^ 1]);
    }
    gridbar(bar_e++, bk);
    {  // conductor L1: kh0 = ih(hc0new), kh1 = hh(hc1 old); 64+64
      const int wo = kh ? OFF_CHH1 : OFF_CIH1;
      const uint* xb = kh ? g_hc1f[p] : g_hc0f[p ^ 1];
      F2 s1 = dot2b(&ldsW[wo + r * PHH], xb, 64, bE);
      F2 s2 = dot2b(&ldsW[wo + r * PHH + 256], xb + 64 * 128, 64, bE);
      float cb = kh ? 0.f : cb1v;
      reduce_update(s1.e + s2.e + cb, s1.o + s2.o + cb,
                    ccE1, ccO1, g_hc1f[p ^ 1]);
    }
    gridbar(bar_e++, bk);
    proj(OFF_PW, coutbv, g_hc1f[p ^ 1], true,
         g_embsF[s] + (bk >> 2) * 128 + (bk & 3), nullptr);
    gridbar(bar_e++, bk);
  }

  // ======================== DECODER ======================================
  stage(OFF_IH0, PIH0, g_dWih0f, 456, 49);   // prev-part only (196 u32/row)
  stage(OFF_HH0, PHH,  g_dWhh0f, 512, 128);
  stage(OFF_IH1, PHH,  g_dWih1f, 512, 128);
  stage(OFF_HH1, PHH,  g_dWhh1f, 512, 128);
  __syncthreads();

  for (int s = 0; s < kNSUB; ++s) {
    float cE0 = P.cdi[(((size_t)(s * 2    ) * 32 + bE    )) * 1024 + j];
    float cO0 = P.cdi[(((size_t)(s * 2    ) * 32 + bE + 1)) * 1024 + j];
    float cE1 = P.cdi[(((size_t)(s * 2 + 1) * 32 + bE    )) * 1024 + j];
    float cO1 = P.cdi[(((size_t)(s * 2 + 1) * 32 + bE + 1)) * 1024 + j];
    {
      // h-state init: one u32 (channel pair) per task -> sc1-storable
      int gid = bk * NTHR + tid;
      if (gid < 32768) {
        int which = gid >> 14;           // 0: h0, 1: h1
        int idx = gid & 16383;
        int jp = idx & 511, bb = idx >> 9;
        int jj = jp * 2;
        const float* src =
            P.hdi + (((size_t)(s * 2 + which)) * 32 + bb) * 1024 + jj;
        uint* dst = which ? g_h1f[0] : g_h0f[0];
        astore(&dst[(jp >> 2) * 128 + bb * 4 + (jp & 3)],
               packh2(src[0], src[1]));
      }
    }
    // emb-part of L0 ih dot (once per 16 steps): weights global, emb f32 T4
    F2 ep = dot2b_f(g_dWih0f + (size_t)grow * 456 + 196 + kh * 128,
                    g_embsF[s] + kh * 64 * 128, 32, bE);
    gridbar(bar_e++, bk);

    for (int t = 0; t < kSTEPS; ++t) {
      const int q = t & 1;
      {  // L0: kh0 = prev(49 f32-chunks) + hh[0:40); kh1 = hh[40:84)+[84:128)
        F2 s1 = kh ? dot2b(&ldsW[OFF_HH0 + r * PHH + 160],
                           g_h0f[q] + 40 * 128, 44, bE)
                   : dot2b_f(&ldsW[OFF_IH0 + r * PIH0], g_xprevF, 49, bE);
        const uint* w2 = &ldsW[OFF_HH0 + r * PHH + (kh ? 336 : 0)];
        const uint* x2 = g_h0f[q] + (kh ? 84 * 128 : 0);
        F2 s2 = dot2b(w2, x2, kh ? 44 : 40, bE);
        float ex = kh ? 0.f : db0v;
        reduce_update(s1.e + s2.e + ep.e + ex, s1.o + s2.o + ep.o + ex,
                      cE0, cO0, g_h0f[q ^ 1]);
      }
      gridbar(bar_e++, bk);
      {  // L1: kh0 = ih(h0new), kh1 = hh(h1 old)
        const int wo = kh ? OFF_HH1 : OFF_IH1;
        const uint* xb = kh ? g_h1f[q] : g_h0f[q ^ 1];
        F2 s1 = dot2b(&ldsW[wo + r * PHH], xb, 64, bE);
        F2 s2 = dot2b(&ldsW[wo + r * PHH + 256], xb + 64 * 128, 64, bE);
        float cb = kh ? 0.f : db1v;
        reduce_update(s1.e + s2.e + cb, s1.o + s2.o + cb,
                      cE1, cO1, g_h1f[q ^ 1]);
      }
      gridbar(bar_e++, bk);
      proj(OFF_PW + 544, doutbv, g_h1f[q ^ 1], bk < kINP,
           g_xprevF + (bk >> 2) * 128 + (bk & 3),
           P.out + (size_t)pb * (kSEQ * kINP) + (size_t)(s * kSTEPS + t) * kINP + bk);
      gridbar(bar_e++, bk);
    }
  }
}

// ---------------------------------------------------------------------------
// Prep: f32 -> f16 weight conversion (+ dWih0 remap), zero state + barrier.
// ---------------------------------------------------------------------------
struct PrepParams {
  const float* cWhh0; const float* cWih1; const float* cWhh1;
  const float* dWih0; const float* dWhh0; const float* dWih1; const float* dWhh1;
  const float* dOutW; const float* cOutW;
};

__device__ __forceinline__ void cvt_mat(const float* __restrict__ src,
                                        uint* __restrict__ dst, int nU32,
                                        int gid0, int gstride) {
  for (int i = gid0; i < nU32; i += gstride) {
    float2 v = ((const float2*)src)[i];
    dst[i] = packh2(v.x, v.y);
  }
}

__global__ void prep_kernel(PrepParams P) {
  int gid0 = blockIdx.x * blockDim.x + threadIdx.x;
  int gs = gridDim.x * blockDim.x;
  cvt_mat(P.cWhh0, g_cWhh0f, 4096 * 512, gid0, gs);
  cvt_mat(P.cWih1, g_cWih1f, 4096 * 512, gid0, gs);
  cvt_mat(P.cWhh1, g_cWhh1f, 4096 * 512, gid0, gs);
  cvt_mat(P.dWhh0, g_dWhh0f, 4096 * 512, gid0, gs);
  cvt_mat(P.dWih1, g_dWih1f, 4096 * 512, gid0, gs);
  cvt_mat(P.dWhh1, g_dWhh1f, 4096 * 512, gid0, gs);
  cvt_mat(P.dOutW, g_dOutWf,  389 * 512, gid0, gs);
  cvt_mat(P.cOutW, g_cOutWf,  512 * 512, gid0, gs);
  // dWih0 remap: f16 col layout [0..388 prev][389..391 z][392..903 emb][pad]
  for (int i = gid0; i < 4096 * 456; i += gs) {
    int rr = i / 456, c2 = i - rr * 456;
    int c0 = c2 * 2, c1 = c0 + 1;
    const float* row = P.dWih0 + (size_t)rr * 901;
    float v0 = 0.f, v1 = 0.f;
    if (c0 < 389) v0 = row[c0];
    else if (c0 >= 392 && c0 < 904) v0 = row[c0 - 3];
    if (c1 < 389) v1 = row[c1];
    else if (c1 >= 392 && c1 < 904) v1 = row[c1 - 3];
    g_dWih0f[i] = packh2(v0, v1);
  }
  // zero initial states
  for (int i = gid0; i < 98 * 128; i += gs) g_xprevF[i] = 0u;
  for (int i = gid0; i < 16384; i += gs) {
    g_hc0f[0][i] = 0u;
    g_hc1f[0][i] = 0u;
  }
  // zero barrier state (every launch -> deterministic graph replays)
  for (int i = gid0; i < 64; i += gs) g_barL[i] = 0u;
  for (int i = gid0; i < 8; i += gs) g_barM[i] = 0u;
  for (int i = gid0; i < 8 * 32; i += gs) g_relM[i] = 0u;
  for (int i = gid0; i < 64 * 32; i += gs) g_relL[i] = 0u;
  if (gid0 == 0) g_barR = 0u;
}

extern "C" void kernel_launch(void* const* d_in, const int* in_sizes, int n_in,
                              void* d_out, int out_size, void* d_ws, size_t ws_size,
                              hipStream_t stream) {
  const float* latent = (const float*)d_in[0];
  const float* hdi   = (const float*)d_in[2];
  const float* cdi   = (const float*)d_in[3];
  const float* cWih0 = (const float*)d_in[4];
  const float* cWhh0 = (const float*)d_in[5];
  const float* cb0   = (const float*)d_in[6];
  const float* cWih1 = (const float*)d_in[7];
  const float* cWhh1 = (const float*)d_in[8];
  const float* cb1   = (const float*)d_in[9];
  const float* cOutW = (const float*)d_in[10];
  const float* cOutb = (const float*)d_in[11];
  const float* dWih0 = (const float*)d_in[12];
  const float* dWhh0 = (const float*)d_in[13];
  const float* db0   = (const float*)d_in[14];
  const float* dWih1 = (const float*)d_in[15];
  const float* dWhh1 = (const float*)d_in[16];
  const float* db1   = (const float*)d_in[17];
  const float* dOutW = (const float*)d_in[18];
  const float* dOutb = (const float*)d_in[19];
  float* out = (float*)d_out;

  PrepParams pp;
  pp.cWhh0 = cWhh0; pp.cWih1 = cWih1; pp.cWhh1 = cWhh1;
  pp.dWih0 = dWih0; pp.dWhh0 = dWhh0; pp.dWih1 = dWih1; pp.dWhh1 = dWhh1;
  pp.dOutW = dOutW; pp.cOutW = cOutW;
  hipLaunchKernelGGL(prep_kernel, dim3(2048), dim3(256), 0, stream, pp);

  KParams hp;
  hp.latent = latent;
  hp.cWih0 = cWih0; hp.cb0 = cb0; hp.cb1 = cb1;
  hp.db0 = db0; hp.db1 = db1;
  hp.cOutb = cOutb; hp.dOutb = dOutb;
  hp.hdi = hdi; hp.cdi = cdi;
  hp.out = out;

  void* args[] = { &hp };
  hipLaunchCooperativeKernel((void*)decoder_persistent, dim3(NBLK), dim3(NTHR),
                             args, 0, stream);
}